// Round 2
// baseline (7705.463 us; speedup 1.0000x reference)
//
#include <hip/hip_runtime.h>
#include <math.h>

// Problem constants
#define BB 2
#define SS 2048
#define EE 1024
#define HH 16
#define HD 64
#define FFF 4096
#define MROWS (BB * SS)        // 4096
#define EPS_F 1.1920929e-7f

// ---------------------------------------------------------------------------
// RMSNorm: one block per row, fp32 accumulate
// ---------------------------------------------------------------------------
__global__ __launch_bounds__(256) void rmsnorm_kernel(const float* __restrict__ x,
                                                      const float* __restrict__ g,
                                                      float* __restrict__ out,
                                                      int cols) {
    int row = blockIdx.x;
    const float* xr = x + (size_t)row * cols;
    float ss = 0.0f;
    for (int c = threadIdx.x; c < cols; c += 256) {
        float v = xr[c];
        ss += v * v;
    }
    for (int off = 32; off > 0; off >>= 1) ss += __shfl_xor(ss, off, 64);
    __shared__ float red[4];
    int wave = threadIdx.x >> 6;
    if ((threadIdx.x & 63) == 0) red[wave] = ss;
    __syncthreads();
    float tot = red[0] + red[1] + red[2] + red[3];
    float rs = rsqrtf(tot / (float)cols + EPS_F);
    float* orow = out + (size_t)row * cols;
    for (int c = threadIdx.x; c < cols; c += 256) {
        orow[c] = xr[c] * rs * g[c];
    }
}

// ---------------------------------------------------------------------------
// Tiled GEMM: C[M,N] = A[M,K] @ W[K,N] + bias[N], fused epilogues
//   mode 0: none; 1: += aux[idx] (residual); 2: exact GELU; 3: *= aux[idx]
// ---------------------------------------------------------------------------
#define Bb_M 64
#define Bb_N 64
#define Bb_K 16

__global__ __launch_bounds__(256) void gemm_kernel(const float* __restrict__ A,
                                                   const float* __restrict__ W,
                                                   const float* __restrict__ bias,
                                                   const float* __restrict__ aux,
                                                   float* __restrict__ C,
                                                   int M, int N, int K, int mode) {
    __shared__ float As[Bb_M][Bb_K + 1];
    __shared__ float Bs[Bb_K][Bb_N + 1];
    int tid = threadIdx.x;
    int row0 = blockIdx.y * Bb_M;
    int col0 = blockIdx.x * Bb_N;
    int tx = tid & 15;        // 0..15 -> cols
    int ty = tid >> 4;        // 0..15 -> rows
    float acc[4][4] = {};

    for (int k0 = 0; k0 < K; k0 += Bb_K) {
        for (int i = tid; i < Bb_M * Bb_K; i += 256) {
            int r = i >> 4, c = i & 15;
            As[r][c] = A[(size_t)(row0 + r) * K + (k0 + c)];
        }
        for (int i = tid; i < Bb_K * Bb_N; i += 256) {
            int r = i >> 6, c = i & 63;
            Bs[r][c] = W[(size_t)(k0 + r) * N + (col0 + c)];
        }
        __syncthreads();
#pragma unroll
        for (int kk = 0; kk < Bb_K; ++kk) {
            float a[4], b[4];
#pragma unroll
            for (int i = 0; i < 4; ++i) a[i] = As[ty * 4 + i][kk];
#pragma unroll
            for (int j = 0; j < 4; ++j) b[j] = Bs[kk][tx * 4 + j];
#pragma unroll
            for (int i = 0; i < 4; ++i)
#pragma unroll
                for (int j = 0; j < 4; ++j) acc[i][j] += a[i] * b[j];
        }
        __syncthreads();
    }

#pragma unroll
    for (int i = 0; i < 4; ++i) {
        int r = row0 + ty * 4 + i;
#pragma unroll
        for (int j = 0; j < 4; ++j) {
            int cc = col0 + tx * 4 + j;
            float c = acc[i][j] + bias[cc];
            size_t idx = (size_t)r * N + cc;
            if (mode == 1)      c += aux[idx];
            else if (mode == 2) c = 0.5f * c * (1.0f + erff(c * 0.70710678118654752f));
            else if (mode == 3) c *= aux[idx];
            C[idx] = c;
        }
    }
}

// ---------------------------------------------------------------------------
// RoPE (half-split), in place. t is (MROWS, heads*64) row-major; pos = row % SS.
// ---------------------------------------------------------------------------
__global__ __launch_bounds__(256) void rope_kernel(float* __restrict__ t, int heads, int total) {
    int idx = blockIdx.x * 256 + threadIdx.x;
    if (idx >= total) return;
    int i = idx & 31;
    int h = (idx >> 5) % heads;
    int row = idx / (32 * heads);
    int s = row & (SS - 1);
    float inv = powf(10000.0f, -(float)i / 32.0f);
    float ang = (float)s * inv;
    float c = cosf(ang), sn = sinf(ang);
    size_t base = (size_t)row * heads * 64 + h * 64 + i;
    float t1 = t[base];
    float t2 = t[base + 32];
    t[base]      = t1 * c - t2 * sn;
    t[base + 32] = t1 * sn + t2 * c;
}

// ---------------------------------------------------------------------------
// Attention: one wave (64 threads) per (b, h, q-row). lane = head dim.
// Online softmax; score via xor-butterfly wave reduction.
// ---------------------------------------------------------------------------
__global__ __launch_bounds__(64) void attn_kernel(const float* __restrict__ q,
                                                  const float* __restrict__ k,
                                                  const float* __restrict__ v,
                                                  float* __restrict__ o) {
    int row = blockIdx.x;          // 0..SS-1
    int h   = blockIdx.y;          // 0..HH-1
    int b   = blockIdx.z;          // 0..BB-1
    int lane = threadIdx.x;        // 0..63 = dim

    size_t qidx = ((size_t)(b * SS + row) * (HH * HD)) + h * HD + lane;
    float qd = q[qidx] * 0.125f;   // 1/sqrt(64)

    float m = -INFINITY, l = 0.0f, acc = 0.0f;
    const float* kb = k + (size_t)b * SS * HD;
    const float* vb = v + (size_t)b * SS * HD;

    for (int j = 0; j <= row; ++j) {
        float s = qd * kb[(size_t)j * HD + lane];
        for (int off = 32; off > 0; off >>= 1) s += __shfl_xor(s, off, 64);
        float mn = fmaxf(m, s);
        float alpha = __expf(m - mn);     // exp(-inf)=0 on first iter
        float p = __expf(s - mn);
        l = l * alpha + p;
        acc = acc * alpha + p * vb[(size_t)j * HD + lane];
        m = mn;
    }
    o[qidx] = acc / l;
}

// ---------------------------------------------------------------------------
// Launch. Workspace layout (fp32, MB offsets):
//   h1@0..16, qb@16..32, kb@32..33, vb@33..34, ao@34..50, x2@50..66,
//   h2@0 (reuse h1, dead after QKV), gg@66..130?  -- see compact plan below.
// Compact reuse plan (~98 MB):
//   h1 @0   (16 MB)   dead after step 4
//   qb @16  (16 MB)   dead after step 7
//   kb @32  (1 MB), vb @33 (1 MB)  dead after step 7
//   ao @34  (16 MB)   dead after step 8
//   x2 @0   (reuse h1) ALIVE to end
//   h2 @16  (reuse qb)
//   gg @34  (64 MB, spans dead kb/vb/ao) -> total 98 MB
// ---------------------------------------------------------------------------
#define MB (1024ull * 1024ull)

extern "C" void kernel_launch(void* const* d_in, const int* in_sizes, int n_in,
                              void* d_out, int out_size, void* d_ws, size_t ws_size,
                              hipStream_t stream) {
    const float* x  = (const float*)d_in[0];
    const float* wq = (const float*)d_in[1];
    const float* bq = (const float*)d_in[2];
    const float* wk = (const float*)d_in[3];
    const float* bk = (const float*)d_in[4];
    const float* wv = (const float*)d_in[5];
    const float* bv = (const float*)d_in[6];
    const float* wo = (const float*)d_in[7];
    const float* bo = (const float*)d_in[8];
    const float* wg = (const float*)d_in[9];
    const float* bg = (const float*)d_in[10];
    const float* wu = (const float*)d_in[11];
    const float* bu = (const float*)d_in[12];
    const float* wd = (const float*)d_in[13];
    const float* bd = (const float*)d_in[14];
    const float* g1 = (const float*)d_in[15];
    const float* g2 = (const float*)d_in[16];
    float* out = (float*)d_out;

    char* ws = (char*)d_ws;
    float* h1 = (float*)(ws);              // 16 MB
    float* qb = (float*)(ws + 16 * MB);    // 16 MB
    float* kb = (float*)(ws + 32 * MB);    // 1 MB
    float* vb = (float*)(ws + 33 * MB);    // 1 MB
    float* ao = (float*)(ws + 34 * MB);    // 16 MB
    float* x2 = (float*)(ws + 0 * MB);     // reuse h1 slot (h1 dead after QKV)
    float* h2 = (float*)(ws + 16 * MB);    // reuse qb slot (qb dead after attn)
    float* gg = (float*)(ws + 34 * MB);    // 64 MB, over dead kb/vb/ao

    // 1. h1 = rmsnorm(x, g1)
    rmsnorm_kernel<<<MROWS, 256, 0, stream>>>(x, g1, h1, EE);

    // 2-4. q/k/v projections
    gemm_kernel<<<dim3(EE / 64, MROWS / 64), 256, 0, stream>>>(h1, wq, bq, nullptr, qb, MROWS, EE, EE, 0);
    gemm_kernel<<<dim3(HD / 64, MROWS / 64), 256, 0, stream>>>(h1, wk, bk, nullptr, kb, MROWS, HD, EE, 0);
    gemm_kernel<<<dim3(HD / 64, MROWS / 64), 256, 0, stream>>>(h1, wv, bv, nullptr, vb, MROWS, HD, EE, 0);

    // 5-6. RoPE on q and k
    {
        int total_q = MROWS * HH * 32;
        rope_kernel<<<(total_q + 255) / 256, 256, 0, stream>>>(qb, HH, total_q);
        int total_k = MROWS * 1 * 32;
        rope_kernel<<<(total_k + 255) / 256, 256, 0, stream>>>(kb, 1, total_k);
    }

    // 7. attention: ao
    attn_kernel<<<dim3(SS, HH, BB), 64, 0, stream>>>(qb, kb, vb, ao);

    // 8. x2 = ao @ wo + bo + x   (x2 overwrites h1 slot; h1 dead)
    gemm_kernel<<<dim3(EE / 64, MROWS / 64), 256, 0, stream>>>(ao, wo, bo, x, x2, MROWS, EE, EE, 1);

    // 9. h2 = rmsnorm(x2, g2)   (h2 overwrites qb slot; qb dead)
    rmsnorm_kernel<<<MROWS, 256, 0, stream>>>(x2, g2, h2, EE);

    // 10. gg = gelu(h2 @ wg + bg)   (gg overwrites kb/vb/ao slots; dead after step 8)
    gemm_kernel<<<dim3(FFF / 64, MROWS / 64), 256, 0, stream>>>(h2, wg, bg, nullptr, gg, MROWS, FFF, EE, 2);

    // 11. gg = (h2 @ wu + bu) * gg
    gemm_kernel<<<dim3(FFF / 64, MROWS / 64), 256, 0, stream>>>(h2, wu, bu, gg, gg, MROWS, FFF, EE, 3);

    // 12. out = gg @ wd + bd + x2
    gemm_kernel<<<dim3(EE / 64, MROWS / 64), 256, 0, stream>>>(gg, wd, bd, x2, out, MROWS, EE, FFF, 1);
}

// Round 3
// 4178.092 us; speedup vs baseline: 1.8443x; 1.8443x over previous
//
#include <hip/hip_runtime.h>
#include <math.h>

// Problem constants
#define BB 2
#define SS 2048
#define EE 1024
#define HH 16
#define HD 64
#define FFF 4096
#define MROWS (BB * SS)        // 4096
#define EPS_F 1.1920929e-7f

// ---------------------------------------------------------------------------
// RMSNorm: one block per row, fp32 accumulate
// ---------------------------------------------------------------------------
__global__ __launch_bounds__(256) void rmsnorm_kernel(const float* __restrict__ x,
                                                      const float* __restrict__ g,
                                                      float* __restrict__ out,
                                                      int cols) {
    int row = blockIdx.x;
    const float* xr = x + (size_t)row * cols;
    float ss = 0.0f;
    for (int c = threadIdx.x; c < cols; c += 256) {
        float v = xr[c];
        ss += v * v;
    }
    for (int off = 32; off > 0; off >>= 1) ss += __shfl_xor(ss, off, 64);
    __shared__ float red[4];
    int wave = threadIdx.x >> 6;
    if ((threadIdx.x & 63) == 0) red[wave] = ss;
    __syncthreads();
    float tot = red[0] + red[1] + red[2] + red[3];
    float rs = rsqrtf(tot / (float)cols + EPS_F);
    float* orow = out + (size_t)row * cols;
    for (int c = threadIdx.x; c < cols; c += 256) {
        orow[c] = xr[c] * rs * g[c];
    }
}

// ---------------------------------------------------------------------------
// Tiled GEMM: C[M,N] = A[M,K] @ W[K,N] + bias[N], fused epilogues
//   mode 0: none; 1: += aux[idx] (residual); 2: exact GELU; 3: *= aux[idx]
// ---------------------------------------------------------------------------
#define Bb_M 64
#define Bb_N 64
#define Bb_K 16

__global__ __launch_bounds__(256) void gemm_kernel(const float* __restrict__ A,
                                                   const float* __restrict__ W,
                                                   const float* __restrict__ bias,
                                                   const float* __restrict__ aux,
                                                   float* __restrict__ C,
                                                   int M, int N, int K, int mode) {
    __shared__ float As[Bb_M][Bb_K + 1];
    __shared__ float Bs[Bb_K][Bb_N + 1];
    int tid = threadIdx.x;
    int row0 = blockIdx.y * Bb_M;
    int col0 = blockIdx.x * Bb_N;
    int tx = tid & 15;        // 0..15 -> cols
    int ty = tid >> 4;        // 0..15 -> rows
    float acc[4][4] = {};

    for (int k0 = 0; k0 < K; k0 += Bb_K) {
        for (int i = tid; i < Bb_M * Bb_K; i += 256) {
            int r = i >> 4, c = i & 15;
            As[r][c] = A[(size_t)(row0 + r) * K + (k0 + c)];
        }
        for (int i = tid; i < Bb_K * Bb_N; i += 256) {
            int r = i >> 6, c = i & 63;
            Bs[r][c] = W[(size_t)(k0 + r) * N + (col0 + c)];
        }
        __syncthreads();
#pragma unroll
        for (int kk = 0; kk < Bb_K; ++kk) {
            float a[4], b[4];
#pragma unroll
            for (int i = 0; i < 4; ++i) a[i] = As[ty * 4 + i][kk];
#pragma unroll
            for (int j = 0; j < 4; ++j) b[j] = Bs[kk][tx * 4 + j];
#pragma unroll
            for (int i = 0; i < 4; ++i)
#pragma unroll
                for (int j = 0; j < 4; ++j) acc[i][j] += a[i] * b[j];
        }
        __syncthreads();
    }

#pragma unroll
    for (int i = 0; i < 4; ++i) {
        int r = row0 + ty * 4 + i;
#pragma unroll
        for (int j = 0; j < 4; ++j) {
            int cc = col0 + tx * 4 + j;
            float c = acc[i][j] + bias[cc];
            size_t idx = (size_t)r * N + cc;
            if (mode == 1)      c += aux[idx];
            else if (mode == 2) c = 0.5f * c * (1.0f + erff(c * 0.70710678118654752f));
            else if (mode == 3) c *= aux[idx];
            C[idx] = c;
        }
    }
}

// ---------------------------------------------------------------------------
// RoPE (half-split), in place. t is (MROWS, heads*64) row-major; pos = row % SS.
// ---------------------------------------------------------------------------
__global__ __launch_bounds__(256) void rope_kernel(float* __restrict__ t, int heads, int total) {
    int idx = blockIdx.x * 256 + threadIdx.x;
    if (idx >= total) return;
    int i = idx & 31;
    int h = (idx >> 5) % heads;
    int row = idx / (32 * heads);
    int s = row & (SS - 1);
    float inv = powf(10000.0f, -(float)i / 32.0f);
    float ang = (float)s * inv;
    float c = cosf(ang), sn = sinf(ang);
    size_t base = (size_t)row * heads * 64 + h * 64 + i;
    float t1 = t[base];
    float t2 = t[base + 32];
    t[base]      = t1 * c - t2 * sn;
    t[base + 32] = t1 * sn + t2 * c;
}

// ---------------------------------------------------------------------------
// Attention v2: LDS-tiled, flash-style online softmax.
// Block = 256 thr = 4 waves; handles (b, h, 4 consecutive q-rows).
// Per 64-key tile:
//   phase A (lane=key):  s_j = sum_d q_d * K[j][d]  via ds_read_b128
//   phase B:             one max+sum butterfly per tile, p_j -> LDS
//   phase C (lane=dim):  acc_d = acc_d*alpha + sum_j p_j * V[j][d]
// LDS: K/V tiles 64x68 fp32 (pad 68 -> conflict-free), q 4x64, p 4x64. ~37 KB.
// ---------------------------------------------------------------------------
#define TP 68   // padded stride

__global__ __launch_bounds__(256) void attn_kernel(const float* __restrict__ q,
                                                   const float* __restrict__ k,
                                                   const float* __restrict__ v,
                                                   float* __restrict__ o) {
    __shared__ float Ks[64 * TP];
    __shared__ float Vs[64 * TP];
    __shared__ float qs[4 * 64];
    __shared__ float ps[4 * 64];

    int r0 = blockIdx.x * 4;       // first q-row of block
    int h  = blockIdx.y;
    int b  = blockIdx.z;
    int tid = threadIdx.x;
    int wave = tid >> 6;
    int lane = tid & 63;
    int row = r0 + wave;

    // stage the 4 q-rows (pre-scaled by 1/sqrt(64))
    qs[wave * 64 + lane] = q[((size_t)(b * SS + row) * (HH * HD)) + h * HD + lane] * 0.125f;

    const float* kb = k + (size_t)b * SS * HD;
    const float* vb = v + (size_t)b * SS * HD;

    float m = -3.0e38f, l = 0.0f, acc = 0.0f;
    int ntiles = (r0 >> 6) + 1;    // r0%64 <= 60, so r0+3 is in the same tile

    for (int t = 0; t < ntiles; ++t) {
        int base = t << 6;
        __syncthreads();
        // stage K,V tile: 64 rows x 64 floats each, float4 per thread
        for (int i = tid; i < 64 * 16; i += 256) {
            int r = i >> 4;
            int c4 = (i & 15) << 2;
            size_t gidx = (size_t)(base + r) * HD + c4;
            *(float4*)&Ks[r * TP + c4] = *(const float4*)&kb[gidx];
            *(float4*)&Vs[r * TP + c4] = *(const float4*)&vb[gidx];
        }
        __syncthreads();

        if (base <= row) {
            // phase A: lane = key index j = base + lane
            float s = 0.0f;
#pragma unroll
            for (int d = 0; d < 64; d += 4) {
                float4 k4 = *(float4*)&Ks[lane * TP + d];
                float4 q4 = *(float4*)&qs[wave * 64 + d];
                s += k4.x * q4.x + k4.y * q4.y + k4.z * q4.z + k4.w * q4.w;
            }
            if (base + lane > row) s = -3.0e38f;   // causal mask

            // phase B: tile max / sum (one butterfly pair per 64 keys)
            float tm = s;
            for (int off = 32; off > 0; off >>= 1) tm = fmaxf(tm, __shfl_xor(tm, off, 64));
            float mn = fmaxf(m, tm);
            float alpha = __expf(m - mn);
            float p = __expf(s - mn);
            float tsum = p;
            for (int off = 32; off > 0; off >>= 1) tsum += __shfl_xor(tsum, off, 64);
            l = l * alpha + tsum;
            m = mn;
            ps[wave * 64 + lane] = p;   // wave-private: no block barrier needed

            // phase C: lane = dim d
            float a = acc * alpha;
#pragma unroll
            for (int j = 0; j < 64; j += 4) {
                float4 p4 = *(float4*)&ps[wave * 64 + j];
                a += p4.x * Vs[(j + 0) * TP + lane];
                a += p4.y * Vs[(j + 1) * TP + lane];
                a += p4.z * Vs[(j + 2) * TP + lane];
                a += p4.w * Vs[(j + 3) * TP + lane];
            }
            acc = a;
        }
    }

    o[((size_t)(b * SS + row) * (HH * HD)) + h * HD + lane] = acc / l;
}

// ---------------------------------------------------------------------------
// Launch. Workspace reuse plan (~98 MB):
//   h1 @0 (16 MB, dead after QKV) | qb @16 | kb @32 | vb @33 | ao @34 (16)
//   x2 @0 (reuse h1) | h2 @16 (reuse qb) | gg @34 (64 MB over dead kb/vb/ao)
// ---------------------------------------------------------------------------
#define MB (1024ull * 1024ull)

extern "C" void kernel_launch(void* const* d_in, const int* in_sizes, int n_in,
                              void* d_out, int out_size, void* d_ws, size_t ws_size,
                              hipStream_t stream) {
    const float* x  = (const float*)d_in[0];
    const float* wq = (const float*)d_in[1];
    const float* bq = (const float*)d_in[2];
    const float* wk = (const float*)d_in[3];
    const float* bk = (const float*)d_in[4];
    const float* wv = (const float*)d_in[5];
    const float* bv = (const float*)d_in[6];
    const float* wo = (const float*)d_in[7];
    const float* bo = (const float*)d_in[8];
    const float* wg = (const float*)d_in[9];
    const float* bg = (const float*)d_in[10];
    const float* wu = (const float*)d_in[11];
    const float* bu = (const float*)d_in[12];
    const float* wd = (const float*)d_in[13];
    const float* bd = (const float*)d_in[14];
    const float* g1 = (const float*)d_in[15];
    const float* g2 = (const float*)d_in[16];
    float* out = (float*)d_out;

    char* ws = (char*)d_ws;
    float* h1 = (float*)(ws);              // 16 MB
    float* qb = (float*)(ws + 16 * MB);    // 16 MB
    float* kb = (float*)(ws + 32 * MB);    // 1 MB
    float* vb = (float*)(ws + 33 * MB);    // 1 MB
    float* ao = (float*)(ws + 34 * MB);    // 16 MB
    float* x2 = (float*)(ws + 0 * MB);     // reuse h1 slot
    float* h2 = (float*)(ws + 16 * MB);    // reuse qb slot
    float* gg = (float*)(ws + 34 * MB);    // 64 MB over dead kb/vb/ao

    // 1. h1 = rmsnorm(x, g1)
    rmsnorm_kernel<<<MROWS, 256, 0, stream>>>(x, g1, h1, EE);

    // 2-4. q/k/v projections
    gemm_kernel<<<dim3(EE / 64, MROWS / 64), 256, 0, stream>>>(h1, wq, bq, nullptr, qb, MROWS, EE, EE, 0);
    gemm_kernel<<<dim3(HD / 64, MROWS / 64), 256, 0, stream>>>(h1, wk, bk, nullptr, kb, MROWS, HD, EE, 0);
    gemm_kernel<<<dim3(HD / 64, MROWS / 64), 256, 0, stream>>>(h1, wv, bv, nullptr, vb, MROWS, HD, EE, 0);

    // 5-6. RoPE on q and k
    {
        int total_q = MROWS * HH * 32;
        rope_kernel<<<(total_q + 255) / 256, 256, 0, stream>>>(qb, HH, total_q);
        int total_k = MROWS * 1 * 32;
        rope_kernel<<<(total_k + 255) / 256, 256, 0, stream>>>(kb, 1, total_k);
    }

    // 7. attention: ao
    attn_kernel<<<dim3(SS / 4, HH, BB), 256, 0, stream>>>(qb, kb, vb, ao);

    // 8. x2 = ao @ wo + bo + x
    gemm_kernel<<<dim3(EE / 64, MROWS / 64), 256, 0, stream>>>(ao, wo, bo, x, x2, MROWS, EE, EE, 1);

    // 9. h2 = rmsnorm(x2, g2)
    rmsnorm_kernel<<<MROWS, 256, 0, stream>>>(x2, g2, h2, EE);

    // 10. gg = gelu(h2 @ wg + bg)
    gemm_kernel<<<dim3(FFF / 64, MROWS / 64), 256, 0, stream>>>(h2, wg, bg, nullptr, gg, MROWS, FFF, EE, 2);

    // 11. gg = (h2 @ wu + bu) * gg
    gemm_kernel<<<dim3(FFF / 64, MROWS / 64), 256, 0, stream>>>(h2, wu, bu, gg, gg, MROWS, FFF, EE, 3);

    // 12. out = gg @ wd + bd + x2
    gemm_kernel<<<dim3(EE / 64, MROWS / 64), 256, 0, stream>>>(gg, wd, bd, x2, out, MROWS, EE, FFF, 1);
}

// Round 4
// 1532.472 us; speedup vs baseline: 5.0281x; 2.7264x over previous
//
#include <hip/hip_runtime.h>
#include <hip/hip_bf16.h>
#include <math.h>

// Problem constants
#define BB 2
#define SS 2048
#define EE 1024
#define HH 16
#define HD 64
#define FFF 4096
#define MROWS (BB * SS)        // 4096
#define EPS_F 1.1920929e-7f

typedef __hip_bfloat16 bf16;
typedef __attribute__((ext_vector_type(8))) short short8;
typedef __attribute__((ext_vector_type(4))) float floatx4;

// ---------------------------------------------------------------------------
// RMSNorm: fp32 in, bf16 out (feeds MFMA GEMMs)
// ---------------------------------------------------------------------------
__global__ __launch_bounds__(256) void rmsnorm_kernel(const float* __restrict__ x,
                                                      const float* __restrict__ g,
                                                      bf16* __restrict__ out,
                                                      int cols) {
    int row = blockIdx.x;
    const float* xr = x + (size_t)row * cols;
    float ss = 0.0f;
    for (int c = threadIdx.x; c < cols; c += 256) {
        float v = xr[c];
        ss += v * v;
    }
    for (int off = 32; off > 0; off >>= 1) ss += __shfl_xor(ss, off, 64);
    __shared__ float red[4];
    int wave = threadIdx.x >> 6;
    if ((threadIdx.x & 63) == 0) red[wave] = ss;
    __syncthreads();
    float tot = red[0] + red[1] + red[2] + red[3];
    float rs = rsqrtf(tot / (float)cols + EPS_F);
    bf16* orow = out + (size_t)row * cols;
    for (int c = threadIdx.x; c < cols; c += 256) {
        orow[c] = __float2bfloat16(xr[c] * rs * g[c]);
    }
}

// ---------------------------------------------------------------------------
// Cast + transpose: W (K x N, fp32) -> Wt (N x K, bf16). 32x32 LDS tiles.
// ---------------------------------------------------------------------------
__global__ __launch_bounds__(256) void transpose_cast_kernel(const float* __restrict__ W,
                                                             bf16* __restrict__ Wt,
                                                             int K, int N) {
    __shared__ float t[32][33];
    int n0 = blockIdx.x * 32, k0 = blockIdx.y * 32;
    int tx = threadIdx.x & 31, ty = threadIdx.x >> 5;   // ty 0..7
#pragma unroll
    for (int i = 0; i < 4; ++i) {
        int kk = ty + i * 8;
        t[kk][tx] = W[(size_t)(k0 + kk) * N + n0 + tx];
    }
    __syncthreads();
#pragma unroll
    for (int i = 0; i < 4; ++i) {
        int nn = ty + i * 8;
        Wt[(size_t)(n0 + nn) * K + k0 + tx] = __float2bfloat16(t[tx][nn]);
    }
}

// pack [bk | bv] -> bkv (128 floats)
__global__ void pack_bkv_kernel(const float* __restrict__ bk, const float* __restrict__ bv,
                                float* __restrict__ bkv) {
    int t = threadIdx.x;
    bkv[t] = (t < 64) ? bk[t] : bv[t - 64];
}

// ---------------------------------------------------------------------------
// bf16 MFMA GEMM: C[M,N] = A[M,K] @ Bt[N,K]^T + bias, fused epilogues.
// 128x128 tile, BK=64, 4 waves, each wave = 4x4 grid of 16x16x32 MFMAs.
// mode: 0 none; 1 += fp32 aux; 2 exact GELU; 3 *= bf16 aux.  obf: bf16 out.
// ---------------------------------------------------------------------------
#define GM 128
#define GN 128
#define GK 64
#define LSTR 72   // padded LDS stride (bf16 elems): 2-way bank alias = free

__global__ __launch_bounds__(256) void gemm_bf16_kernel(
        const bf16* __restrict__ A, const bf16* __restrict__ Bt,
        const float* __restrict__ bias, const void* __restrict__ aux,
        void* __restrict__ C, int M, int N, int K, int mode, int obf) {
    __shared__ short As[GM * LSTR];
    __shared__ short Bs[GN * LSTR];
    int tid = threadIdx.x;
    int wave = tid >> 6, lane = tid & 63;
    int wm = (wave >> 1) * 64, wn = (wave & 1) * 64;
    int row0 = blockIdx.y * GM, col0 = blockIdx.x * GN;
    int lr = lane & 15, lq = lane >> 4;

    floatx4 acc[4][4];
#pragma unroll
    for (int mi = 0; mi < 4; ++mi)
#pragma unroll
        for (int ni = 0; ni < 4; ++ni)
            acc[mi][ni] = (floatx4){0.f, 0.f, 0.f, 0.f};

    for (int k0 = 0; k0 < K; k0 += GK) {
        __syncthreads();
        // stage A and Bt tiles: 128 rows x 64 bf16 each; 16B chunks
#pragma unroll
        for (int i = 0; i < 4; ++i) {
            int ch = i * 256 + tid;            // 0..1023
            int m = ch >> 3, kc = (ch & 7) << 3;
            int4 da = *(const int4*)(A + (size_t)(row0 + m) * K + k0 + kc);
            *(int4*)&As[m * LSTR + kc] = da;
            int4 db = *(const int4*)(Bt + (size_t)(col0 + m) * K + k0 + kc);
            *(int4*)&Bs[m * LSTR + kc] = db;
        }
        __syncthreads();
#pragma unroll
        for (int ks = 0; ks < GK; ks += 32) {
            short8 af[4], bfr[4];
#pragma unroll
            for (int mi = 0; mi < 4; ++mi)
                af[mi] = *(const short8*)&As[(wm + mi * 16 + lr) * LSTR + ks + lq * 8];
#pragma unroll
            for (int ni = 0; ni < 4; ++ni)
                bfr[ni] = *(const short8*)&Bs[(wn + ni * 16 + lr) * LSTR + ks + lq * 8];
#pragma unroll
            for (int mi = 0; mi < 4; ++mi)
#pragma unroll
                for (int ni = 0; ni < 4; ++ni)
                    acc[mi][ni] = __builtin_amdgcn_mfma_f32_16x16x32_bf16(
                        af[mi], bfr[ni], acc[mi][ni], 0, 0, 0);
        }
    }

    // epilogue: C/D layout col=lane&15, row=(lane>>4)*4+reg
#pragma unroll
    for (int mi = 0; mi < 4; ++mi) {
#pragma unroll
        for (int ni = 0; ni < 4; ++ni) {
            int gc = col0 + wn + ni * 16 + lr;
            float bv = bias[gc];
#pragma unroll
            for (int r = 0; r < 4; ++r) {
                int gr = row0 + wm + mi * 16 + lq * 4 + r;
                size_t idx = (size_t)gr * N + gc;
                float c = acc[mi][ni][r] + bv;
                if (mode == 1)      c += ((const float*)aux)[idx];
                else if (mode == 2) c = 0.5f * c * (1.0f + erff(c * 0.70710678118654752f));
                else if (mode == 3) c *= (float)((const bf16*)aux)[idx];
                if (obf) ((bf16*)C)[idx] = __float2bfloat16(c);
                else     ((float*)C)[idx] = c;
            }
        }
    }
}

// ---------------------------------------------------------------------------
// RoPE (half-split), in place, strided. pos = row % SS.
// ---------------------------------------------------------------------------
__global__ __launch_bounds__(256) void rope_kernel(float* __restrict__ t, int heads,
                                                   int rowstride, int total) {
    int idx = blockIdx.x * 256 + threadIdx.x;
    if (idx >= total) return;
    int i = idx & 31;
    int h = (idx >> 5) % heads;
    int row = idx / (32 * heads);
    int s = row & (SS - 1);
    float inv = powf(10000.0f, -(float)i / 32.0f);
    float ang = (float)s * inv;
    float c = cosf(ang), sn = sinf(ang);
    size_t base = (size_t)row * rowstride + h * 64 + i;
    float t1 = t[base];
    float t2 = t[base + 32];
    t[base]      = t1 * c - t2 * sn;
    t[base + 32] = t1 * sn + t2 * c;
}

// ---------------------------------------------------------------------------
// Attention: LDS-tiled flash-style. Block = 4 waves = (b, h, 4 q-rows).
// q: (MROWS, 1024) fp32. kv: (MROWS, 128) fp32, K at +0, V at +64. out bf16.
// ---------------------------------------------------------------------------
#define TP 68   // padded stride

__global__ __launch_bounds__(256) void attn_kernel(const float* __restrict__ q,
                                                   const float* __restrict__ kv,
                                                   bf16* __restrict__ o) {
    __shared__ float Ks[64 * TP];
    __shared__ float Vs[64 * TP];
    __shared__ float qs[4 * 64];
    __shared__ float ps[4 * 64];

    int r0 = blockIdx.x * 4;
    int h  = blockIdx.y;
    int b  = blockIdx.z;
    int tid = threadIdx.x;
    int wave = tid >> 6;
    int lane = tid & 63;
    int row = r0 + wave;

    qs[wave * 64 + lane] = q[((size_t)(b * SS + row) * (HH * HD)) + h * HD + lane] * 0.125f;

    const float* kvb = kv + (size_t)b * SS * 128;

    float m = -3.0e38f, l = 0.0f, acc = 0.0f;
    int ntiles = (r0 >> 6) + 1;

    for (int t = 0; t < ntiles; ++t) {
        int base = t << 6;
        __syncthreads();
        for (int i = tid; i < 64 * 16; i += 256) {
            int r = i >> 4;
            int c4 = (i & 15) << 2;
            size_t gidx = (size_t)(base + r) * 128 + c4;
            *(float4*)&Ks[r * TP + c4] = *(const float4*)&kvb[gidx];
            *(float4*)&Vs[r * TP + c4] = *(const float4*)&kvb[gidx + 64];
        }
        __syncthreads();

        if (base <= row) {
            float s = 0.0f;
#pragma unroll
            for (int d = 0; d < 64; d += 4) {
                float4 k4 = *(float4*)&Ks[lane * TP + d];
                float4 q4 = *(float4*)&qs[wave * 64 + d];
                s += k4.x * q4.x + k4.y * q4.y + k4.z * q4.z + k4.w * q4.w;
            }
            if (base + lane > row) s = -3.0e38f;

            float tm = s;
            for (int off = 32; off > 0; off >>= 1) tm = fmaxf(tm, __shfl_xor(tm, off, 64));
            float mn = fmaxf(m, tm);
            float alpha = __expf(m - mn);
            float p = __expf(s - mn);
            float tsum = p;
            for (int off = 32; off > 0; off >>= 1) tsum += __shfl_xor(tsum, off, 64);
            l = l * alpha + tsum;
            m = mn;
            ps[wave * 64 + lane] = p;

            float a = acc * alpha;
#pragma unroll
            for (int j = 0; j < 64; j += 4) {
                float4 p4 = *(float4*)&ps[wave * 64 + j];
                a += p4.x * Vs[(j + 0) * TP + lane];
                a += p4.y * Vs[(j + 1) * TP + lane];
                a += p4.z * Vs[(j + 2) * TP + lane];
                a += p4.w * Vs[(j + 3) * TP + lane];
            }
            acc = a;
        }
    }

    o[((size_t)(b * SS + row) * (HH * HD)) + h * HD + lane] = __float2bfloat16(acc / l);
}

// ---------------------------------------------------------------------------
// Launch. Workspace (byte offsets, ~87 MB):
//   qb   @0    16 MB fp32  (dead after attn; wgT/wuT reuse)
//   x2   @16M  16 MB fp32  (alive to end)
//   h1b  @32M   8 MB bf16  (h1; reused as h2 after attn)
//   kv   @40M   2 MB fp32
//   ao   @42M   8 MB bf16  (dead after wo GEMM; wdT reuses)
//   gg   @50M  32 MB bf16
//   wqT  @82M   2 MB | wkvT @84M 0.25 MB | bkv @84.5M | woT @85M 2 MB
//   wgT  @0, wuT @8M (over qb) | wdT @42M (over ao)
// ---------------------------------------------------------------------------
#define MB (1024ull * 1024ull)

extern "C" void kernel_launch(void* const* d_in, const int* in_sizes, int n_in,
                              void* d_out, int out_size, void* d_ws, size_t ws_size,
                              hipStream_t stream) {
    const float* x  = (const float*)d_in[0];
    const float* wq = (const float*)d_in[1];
    const float* bq = (const float*)d_in[2];
    const float* wk = (const float*)d_in[3];
    const float* bk = (const float*)d_in[4];
    const float* wv = (const float*)d_in[5];
    const float* bv = (const float*)d_in[6];
    const float* wo = (const float*)d_in[7];
    const float* bo = (const float*)d_in[8];
    const float* wg = (const float*)d_in[9];
    const float* bg = (const float*)d_in[10];
    const float* wu = (const float*)d_in[11];
    const float* bu = (const float*)d_in[12];
    const float* wd = (const float*)d_in[13];
    const float* bd = (const float*)d_in[14];
    const float* g1 = (const float*)d_in[15];
    const float* g2 = (const float*)d_in[16];
    float* out = (float*)d_out;

    char* ws = (char*)d_ws;
    float* qb   = (float*)(ws);
    float* x2   = (float*)(ws + 16 * MB);
    bf16*  h1b  = (bf16*)(ws + 32 * MB);
    float* kv   = (float*)(ws + 40 * MB);
    bf16*  ao   = (bf16*)(ws + 42 * MB);
    bf16*  gg   = (bf16*)(ws + 50 * MB);
    bf16*  wqT  = (bf16*)(ws + 82 * MB);
    bf16*  wkvT = (bf16*)(ws + 84 * MB);
    float* bkv  = (float*)(ws + 84 * MB + 512 * 1024);
    bf16*  woT  = (bf16*)(ws + 85 * MB);
    bf16*  wgT  = (bf16*)(ws);            // over qb (dead after attn)
    bf16*  wuT  = (bf16*)(ws + 8 * MB);   // over qb upper half
    bf16*  wdT  = (bf16*)(ws + 42 * MB);  // over ao (dead after wo GEMM)
    bf16*  h2b  = h1b;                    // h1 dead after QKV GEMMs

    // 1. h1 = rmsnorm(x, g1)  [bf16]
    rmsnorm_kernel<<<MROWS, 256, 0, stream>>>(x, g1, h1b, EE);

    // 2. weight transposes for attention block
    transpose_cast_kernel<<<dim3(EE / 32, EE / 32), 256, 0, stream>>>(wq, wqT, EE, EE);
    transpose_cast_kernel<<<dim3(HD / 32, EE / 32), 256, 0, stream>>>(wk, wkvT, EE, HD);
    transpose_cast_kernel<<<dim3(HD / 32, EE / 32), 256, 0, stream>>>(wv, wkvT + 64 * EE, EE, HD);
    pack_bkv_kernel<<<1, 128, 0, stream>>>(bk, bv, bkv);
    transpose_cast_kernel<<<dim3(EE / 32, EE / 32), 256, 0, stream>>>(wo, woT, EE, EE);

    // 3. qb = h1 @ wq + bq  [fp32 out]
    gemm_bf16_kernel<<<dim3(EE / GN, MROWS / GM), 256, 0, stream>>>(
        h1b, wqT, bq, nullptr, qb, MROWS, EE, EE, 0, 0);
    // 4. kv = h1 @ [wk|wv] + [bk|bv]  [fp32 out, N=128]
    gemm_bf16_kernel<<<dim3(1, MROWS / GM), 256, 0, stream>>>(
        h1b, wkvT, bkv, nullptr, kv, MROWS, 128, EE, 0, 0);

    // 5. RoPE on q and k
    {
        int total_q = MROWS * HH * 32;
        rope_kernel<<<(total_q + 255) / 256, 256, 0, stream>>>(qb, HH, EE, total_q);
        int total_k = MROWS * 32;
        rope_kernel<<<(total_k + 255) / 256, 256, 0, stream>>>(kv, 1, 128, total_k);
    }

    // 6. attention -> ao [bf16]
    attn_kernel<<<dim3(SS / 4, HH, BB), 256, 0, stream>>>(qb, kv, ao);

    // 7. x2 = ao @ wo + bo + x  [fp32 out]
    gemm_bf16_kernel<<<dim3(EE / GN, MROWS / GM), 256, 0, stream>>>(
        ao, woT, bo, x, x2, MROWS, EE, EE, 1, 0);

    // 8. h2 = rmsnorm(x2, g2)  [bf16]
    rmsnorm_kernel<<<MROWS, 256, 0, stream>>>(x2, g2, h2b, EE);

    // 9. FFN weight transposes (reuse dead qb/ao slots)
    transpose_cast_kernel<<<dim3(FFF / 32, EE / 32), 256, 0, stream>>>(wg, wgT, EE, FFF);
    transpose_cast_kernel<<<dim3(FFF / 32, EE / 32), 256, 0, stream>>>(wu, wuT, EE, FFF);

    // 10. gg = gelu(h2 @ wg + bg)  [bf16]
    gemm_bf16_kernel<<<dim3(FFF / GN, MROWS / GM), 256, 0, stream>>>(
        h2b, wgT, bg, nullptr, gg, MROWS, FFF, EE, 2, 1);

    // 11. gg = (h2 @ wu + bu) * gg  [bf16]
    gemm_bf16_kernel<<<dim3(FFF / GN, MROWS / GM), 256, 0, stream>>>(
        h2b, wuT, bu, gg, gg, MROWS, FFF, EE, 3, 1);

    // 12. wd transpose (over dead ao slot), then out = gg @ wd + bd + x2 [fp32]
    transpose_cast_kernel<<<dim3(EE / 32, FFF / 32), 256, 0, stream>>>(wd, wdT, FFF, EE);
    gemm_bf16_kernel<<<dim3(EE / GN, MROWS / GM), 256, 0, stream>>>(
        gg, wdT, bd, x2, out, MROWS, EE, FFF, 1, 0);
}

// Round 5
// 618.010 us; speedup vs baseline: 12.4682x; 2.4797x over previous
//
#include <hip/hip_runtime.h>
#include <hip/hip_bf16.h>
#include <math.h>

// Problem constants
#define BB 2
#define SS 2048
#define EE 1024
#define HH 16
#define HD 64
#define FFF 4096
#define MROWS (BB * SS)        // 4096
#define EPS_F 1.1920929e-7f

typedef __hip_bfloat16 bf16;
typedef __attribute__((ext_vector_type(8))) short short8;
typedef __attribute__((ext_vector_type(4))) float floatx4;

// ---------------------------------------------------------------------------
// RMSNorm: fp32 in, bf16 out
// ---------------------------------------------------------------------------
__global__ __launch_bounds__(256) void rmsnorm_kernel(const float* __restrict__ x,
                                                      const float* __restrict__ g,
                                                      bf16* __restrict__ out,
                                                      int cols) {
    int row = blockIdx.x;
    const float* xr = x + (size_t)row * cols;
    float ss = 0.0f;
    for (int c = threadIdx.x; c < cols; c += 256) {
        float v = xr[c];
        ss += v * v;
    }
    for (int off = 32; off > 0; off >>= 1) ss += __shfl_xor(ss, off, 64);
    __shared__ float red[4];
    int wave = threadIdx.x >> 6;
    if ((threadIdx.x & 63) == 0) red[wave] = ss;
    __syncthreads();
    float tot = red[0] + red[1] + red[2] + red[3];
    float rs = rsqrtf(tot / (float)cols + EPS_F);
    bf16* orow = out + (size_t)row * cols;
    for (int c = threadIdx.x; c < cols; c += 256) {
        orow[c] = __float2bfloat16(xr[c] * rs * g[c]);
    }
}

// ---------------------------------------------------------------------------
// Cast + transpose: W (K x N, fp32) -> Wt (N x K, bf16). 32x32 LDS tiles.
// ---------------------------------------------------------------------------
__global__ __launch_bounds__(256) void transpose_cast_kernel(const float* __restrict__ W,
                                                             bf16* __restrict__ Wt,
                                                             int K, int N) {
    __shared__ float t[32][33];
    int n0 = blockIdx.x * 32, k0 = blockIdx.y * 32;
    int tx = threadIdx.x & 31, ty = threadIdx.x >> 5;   // ty 0..7
#pragma unroll
    for (int i = 0; i < 4; ++i) {
        int kk = ty + i * 8;
        t[kk][tx] = W[(size_t)(k0 + kk) * N + n0 + tx];
    }
    __syncthreads();
#pragma unroll
    for (int i = 0; i < 4; ++i) {
        int nn = ty + i * 8;
        Wt[(size_t)(n0 + nn) * K + k0 + tx] = __float2bfloat16(t[tx][nn]);
    }
}

// pack [bk | bv] -> bkv (128 floats)
__global__ void pack_bkv_kernel(const float* __restrict__ bk, const float* __restrict__ bv,
                                float* __restrict__ bkv) {
    int t = threadIdx.x;
    bkv[t] = (t < 64) ? bk[t] : bv[t - 64];
}

// ---------------------------------------------------------------------------
// bf16 MFMA GEMM: C[M,N] = A[M,K] @ Bt[N,K]^T + bias, fused epilogues.
// mode: 0 none; 1 += fp32 aux; 2 exact GELU; 3 *= bf16 aux.  obf: bf16 out.
// ---------------------------------------------------------------------------
#define GM 128
#define GN 128
#define GK 64
#define LSTR 72

__global__ __launch_bounds__(256) void gemm_bf16_kernel(
        const bf16* __restrict__ A, const bf16* __restrict__ Bt,
        const float* __restrict__ bias, const void* __restrict__ aux,
        void* __restrict__ C, int M, int N, int K, int mode, int obf) {
    __shared__ short As[GM * LSTR];
    __shared__ short Bs[GN * LSTR];
    int tid = threadIdx.x;
    int wave = tid >> 6, lane = tid & 63;
    int wm = (wave >> 1) * 64, wn = (wave & 1) * 64;
    int row0 = blockIdx.y * GM, col0 = blockIdx.x * GN;
    int lr = lane & 15, lq = lane >> 4;

    floatx4 acc[4][4];
#pragma unroll
    for (int mi = 0; mi < 4; ++mi)
#pragma unroll
        for (int ni = 0; ni < 4; ++ni)
            acc[mi][ni] = (floatx4){0.f, 0.f, 0.f, 0.f};

    for (int k0 = 0; k0 < K; k0 += GK) {
        __syncthreads();
#pragma unroll
        for (int i = 0; i < 4; ++i) {
            int ch = i * 256 + tid;
            int m = ch >> 3, kc = (ch & 7) << 3;
            int4 da = *(const int4*)(A + (size_t)(row0 + m) * K + k0 + kc);
            *(int4*)&As[m * LSTR + kc] = da;
            int4 db = *(const int4*)(Bt + (size_t)(col0 + m) * K + k0 + kc);
            *(int4*)&Bs[m * LSTR + kc] = db;
        }
        __syncthreads();
#pragma unroll
        for (int ks = 0; ks < GK; ks += 32) {
            short8 af[4], bfr[4];
#pragma unroll
            for (int mi = 0; mi < 4; ++mi)
                af[mi] = *(const short8*)&As[(wm + mi * 16 + lr) * LSTR + ks + lq * 8];
#pragma unroll
            for (int ni = 0; ni < 4; ++ni)
                bfr[ni] = *(const short8*)&Bs[(wn + ni * 16 + lr) * LSTR + ks + lq * 8];
#pragma unroll
            for (int mi = 0; mi < 4; ++mi)
#pragma unroll
                for (int ni = 0; ni < 4; ++ni)
                    acc[mi][ni] = __builtin_amdgcn_mfma_f32_16x16x32_bf16(
                        af[mi], bfr[ni], acc[mi][ni], 0, 0, 0);
        }
    }

#pragma unroll
    for (int mi = 0; mi < 4; ++mi) {
#pragma unroll
        for (int ni = 0; ni < 4; ++ni) {
            int gc = col0 + wn + ni * 16 + lr;
            float bv = bias[gc];
#pragma unroll
            for (int r = 0; r < 4; ++r) {
                int gr = row0 + wm + mi * 16 + lq * 4 + r;
                size_t idx = (size_t)gr * N + gc;
                float c = acc[mi][ni][r] + bv;
                if (mode == 1)      c += ((const float*)aux)[idx];
                else if (mode == 2) c = 0.5f * c * (1.0f + erff(c * 0.70710678118654752f));
                else if (mode == 3) c *= (float)((const bf16*)aux)[idx];
                if (obf) ((bf16*)C)[idx] = __float2bfloat16(c);
                else     ((float*)C)[idx] = c;
            }
        }
    }
}

// ---------------------------------------------------------------------------
// RoPE on bf16 q, in place, with 1/sqrt(HD) folded in. pos = row % SS.
// ---------------------------------------------------------------------------
__global__ __launch_bounds__(256) void rope_q_kernel(bf16* __restrict__ t, int total) {
    int idx = blockIdx.x * 256 + threadIdx.x;
    if (idx >= total) return;
    int i = idx & 31;
    int h = (idx >> 5) % HH;
    int row = idx / (32 * HH);
    int s = row & (SS - 1);
    float inv = powf(10000.0f, -(float)i / 32.0f);
    float ang = (float)s * inv;
    float c = cosf(ang), sn = sinf(ang);
    size_t base = (size_t)row * (HH * HD) + h * 64 + i;
    float t1 = (float)t[base];
    float t2 = (float)t[base + 32];
    t[base]      = __float2bfloat16((t1 * c - t2 * sn) * 0.125f);
    t[base + 32] = __float2bfloat16((t1 * sn + t2 * c) * 0.125f);
}

// ---------------------------------------------------------------------------
// prep_kv: kv fp32 (MROWS,128) -> kbf bf16 (MROWS,64) with RoPE,
//          vtb bf16 (BB,64,SS) = V transposed per batch.
// grid (SS/64, BB), block 256.
// ---------------------------------------------------------------------------
__global__ __launch_bounds__(256) void prep_kv_kernel(const float* __restrict__ kv,
                                                      bf16* __restrict__ kbf,
                                                      bf16* __restrict__ vtb) {
    __shared__ float vt[64][65];
    int s0 = blockIdx.x * 64;
    int b  = blockIdx.y;
    int tid = threadIdx.x;

    // K rope: 64 rows x 32 pairs = 2048 pairs
    for (int i = tid; i < 2048; i += 256) {
        int sl = i >> 5, ii = i & 31;
        int s = s0 + sl;
        size_t base = ((size_t)(b * SS + s)) * 128;
        float k1 = kv[base + ii], k2 = kv[base + ii + 32];
        float inv = powf(10000.0f, -(float)ii / 32.0f);
        float ang = (float)s * inv;
        float c = cosf(ang), sn = sinf(ang);
        size_t ob = ((size_t)(b * SS + s)) * 64;
        kbf[ob + ii]      = __float2bfloat16(k1 * c - k2 * sn);
        kbf[ob + ii + 32] = __float2bfloat16(k1 * sn + k2 * c);
    }

    // V transpose: load coalesced, store transposed
    for (int i = tid; i < 4096; i += 256) {
        int s = i >> 6, d = i & 63;
        vt[d][s] = kv[((size_t)(b * SS + s0 + s)) * 128 + 64 + d];
    }
    __syncthreads();
    for (int i = tid; i < 4096; i += 256) {
        int d = i >> 6, sl = i & 63;
        vtb[((size_t)(b * 64 + d)) * SS + s0 + sl] = __float2bfloat16(vt[d][sl]);
    }
}

// ---------------------------------------------------------------------------
// MFMA flash attention. Block = 4 waves = (b, h, 64 q-rows); wave owns 16 rows.
// q: (MROWS,1024) bf16 pre-scaled+roped. kbf: (MROWS,64) bf16 roped.
// vtb: (BB,64,SS) bf16. o: (MROWS,1024) bf16.
// ---------------------------------------------------------------------------
#define AST 72
#define PST 72

__global__ __launch_bounds__(256) void attn_mfma_kernel(
        const bf16* __restrict__ q, const bf16* __restrict__ kb,
        const bf16* __restrict__ vt, bf16* __restrict__ o) {
    __shared__ short Ks[64 * AST];        // [key][d]
    __shared__ short Vs[64 * AST];        // [d][key]
    __shared__ short Ps[4][16 * PST];     // per-wave P [row][key]

    int q0 = blockIdx.x * 64;
    int h = blockIdx.y, b = blockIdx.z;
    int tid = threadIdx.x, w = tid >> 6, lane = tid & 63;
    int lr = lane & 15, quad = lane >> 4;

    // Q A-fragments (rows q0+w*16+lr), k-contiguous
    const bf16* qrow = q + ((size_t)(b * SS + q0 + w * 16 + lr)) * (HH * HD) + h * HD;
    short8 qf0 = *(const short8*)(qrow + quad * 8);
    short8 qf1 = *(const short8*)(qrow + 32 + quad * 8);

    floatx4 O[4];
#pragma unroll
    for (int ni = 0; ni < 4; ++ni) O[ni] = (floatx4){0.f, 0.f, 0.f, 0.f};
    float mrow[4] = {-3.0e38f, -3.0e38f, -3.0e38f, -3.0e38f};
    float lrow[4] = {0.f, 0.f, 0.f, 0.f};

    int ntiles = blockIdx.x + 1;
    for (int t = 0; t < ntiles; ++t) {
        int j0 = t * 64;
        __syncthreads();
        // stage K tile (key-major) and VT tile (d-major), 16B per chunk
        for (int i = tid; i < 512; i += 256) {
            int r = i >> 3, c8 = (i & 7) * 8;
            *(short8*)&Ks[r * AST + c8] =
                *(const short8*)(kb + ((size_t)(b * SS + j0 + r)) * 64 + c8);
            *(short8*)&Vs[r * AST + c8] =
                *(const short8*)(vt + ((size_t)(b * 64 + r)) * SS + j0 + c8);
        }
        __syncthreads();

        // S = Q @ K^T  (4 ni frags x 2 k-steps)
        floatx4 S[4];
#pragma unroll
        for (int ni = 0; ni < 4; ++ni) S[ni] = (floatx4){0.f, 0.f, 0.f, 0.f};
#pragma unroll
        for (int ni = 0; ni < 4; ++ni) {
            short8 b0 = *(const short8*)&Ks[(ni * 16 + lr) * AST + quad * 8];
            short8 b1 = *(const short8*)&Ks[(ni * 16 + lr) * AST + 32 + quad * 8];
            S[ni] = __builtin_amdgcn_mfma_f32_16x16x32_bf16(qf0, b0, S[ni], 0, 0, 0);
            S[ni] = __builtin_amdgcn_mfma_f32_16x16x32_bf16(qf1, b1, S[ni], 0, 0, 0);
        }

        // causal mask (diagonal tile only)
        if (t == ntiles - 1) {
            int rowg = q0 + w * 16 + quad * 4;
#pragma unroll
            for (int ni = 0; ni < 4; ++ni) {
                int colg = j0 + ni * 16 + lr;
#pragma unroll
                for (int r = 0; r < 4; ++r)
                    if (colg > rowg + r) S[ni][r] = -3.0e38f;
            }
        }

        // online softmax; rows = quad*4+reg, reduce across the 16 lanes of the quad
        float alpha[4];
#pragma unroll
        for (int r = 0; r < 4; ++r) {
            float mx = fmaxf(fmaxf(S[0][r], S[1][r]), fmaxf(S[2][r], S[3][r]));
            for (int off = 8; off > 0; off >>= 1) mx = fmaxf(mx, __shfl_xor(mx, off, 64));
            float mn = fmaxf(mrow[r], mx);
            alpha[r] = __expf(mrow[r] - mn);
            mrow[r] = mn;
            float psum = 0.f;
#pragma unroll
            for (int ni = 0; ni < 4; ++ni) {
                float p = __expf(S[ni][r] - mn);
                S[ni][r] = p;
                psum += p;
            }
            for (int off = 8; off > 0; off >>= 1) psum += __shfl_xor(psum, off, 64);
            lrow[r] = lrow[r] * alpha[r] + psum;
        }

        // rescale O, write P (bf16) to wave-private LDS in C-layout
#pragma unroll
        for (int ni = 0; ni < 4; ++ni) {
#pragma unroll
            for (int r = 0; r < 4; ++r) {
                O[ni][r] *= alpha[r];
                bf16 pb = __float2bfloat16(S[ni][r]);
                Ps[w][(quad * 4 + r) * PST + ni * 16 + lr] = *(short*)&pb;
            }
        }
        // read P back as A-fragments (same-wave: lgkmcnt ordering suffices)
        short8 p0 = *(const short8*)&Ps[w][lr * PST + quad * 8];
        short8 p1 = *(const short8*)&Ps[w][lr * PST + 32 + quad * 8];

        // O += P @ V  (V as B from VT rows)
#pragma unroll
        for (int ni = 0; ni < 4; ++ni) {
            short8 v0 = *(const short8*)&Vs[(ni * 16 + lr) * AST + quad * 8];
            short8 v1 = *(const short8*)&Vs[(ni * 16 + lr) * AST + 32 + quad * 8];
            O[ni] = __builtin_amdgcn_mfma_f32_16x16x32_bf16(p0, v0, O[ni], 0, 0, 0);
            O[ni] = __builtin_amdgcn_mfma_f32_16x16x32_bf16(p1, v1, O[ni], 0, 0, 0);
        }
    }

    // epilogue: O / l -> o
#pragma unroll
    for (int ni = 0; ni < 4; ++ni) {
        int gc = h * 64 + ni * 16 + lr;
#pragma unroll
        for (int r = 0; r < 4; ++r) {
            int gr = b * SS + q0 + w * 16 + quad * 4 + r;
            o[(size_t)gr * (HH * HD) + gc] = __float2bfloat16(O[ni][r] / lrow[r]);
        }
    }
}

// ---------------------------------------------------------------------------
// Launch. Workspace (byte offsets, ~87 MB):
//   qbf @0 (8 MB bf16, dead after attn; wgT reuses @0)
//   wuT @8M (8 MB, written after attn)
//   x2  @16M (16 MB fp32, alive to end)
//   h1b/h2b @32M (8 MB bf16)
//   kv  @40M (2 MB fp32, dead after prep_kv)
//   ao  @42M (8 MB bf16, dead after wo GEMM; wdT reuses @42M)
//   gg  @50M (32 MB bf16, written step 10) -- kbf @50M, vtb @50.5M live
//       only until attention, before gg is written
//   wqT @82M | wkvT @84M | bkv @84.5M | woT @85M
// ---------------------------------------------------------------------------
#define MB (1024ull * 1024ull)

extern "C" void kernel_launch(void* const* d_in, const int* in_sizes, int n_in,
                              void* d_out, int out_size, void* d_ws, size_t ws_size,
                              hipStream_t stream) {
    const float* x  = (const float*)d_in[0];
    const float* wq = (const float*)d_in[1];
    const float* bq = (const float*)d_in[2];
    const float* wk = (const float*)d_in[3];
    const float* bk = (const float*)d_in[4];
    const float* wv = (const float*)d_in[5];
    const float* bv = (const float*)d_in[6];
    const float* wo = (const float*)d_in[7];
    const float* bo = (const float*)d_in[8];
    const float* wg = (const float*)d_in[9];
    const float* bg = (const float*)d_in[10];
    const float* wu = (const float*)d_in[11];
    const float* bu = (const float*)d_in[12];
    const float* wd = (const float*)d_in[13];
    const float* bd = (const float*)d_in[14];
    const float* g1 = (const float*)d_in[15];
    const float* g2 = (const float*)d_in[16];
    float* out = (float*)d_out;

    char* ws = (char*)d_ws;
    bf16*  qbf  = (bf16*)(ws);
    bf16*  wuT  = (bf16*)(ws + 8 * MB);
    float* x2   = (float*)(ws + 16 * MB);
    bf16*  h1b  = (bf16*)(ws + 32 * MB);
    float* kv   = (float*)(ws + 40 * MB);
    bf16*  ao   = (bf16*)(ws + 42 * MB);
    bf16*  gg   = (bf16*)(ws + 50 * MB);
    bf16*  kbf  = (bf16*)(ws + 50 * MB);            // over gg head (dead by step 10)
    bf16*  vtb  = (bf16*)(ws + 50 * MB + 512 * 1024);
    bf16*  wqT  = (bf16*)(ws + 82 * MB);
    bf16*  wkvT = (bf16*)(ws + 84 * MB);
    float* bkv  = (float*)(ws + 84 * MB + 512 * 1024);
    bf16*  woT  = (bf16*)(ws + 85 * MB);
    bf16*  wgT  = (bf16*)(ws);                       // over qbf (dead after attn)
    bf16*  wdT  = (bf16*)(ws + 42 * MB);             // over ao (dead after wo GEMM)
    bf16*  h2b  = h1b;

    // 1. h1 = rmsnorm(x, g1)
    rmsnorm_kernel<<<MROWS, 256, 0, stream>>>(x, g1, h1b, EE);

    // 2. weight transposes for attention block
    transpose_cast_kernel<<<dim3(EE / 32, EE / 32), 256, 0, stream>>>(wq, wqT, EE, EE);
    transpose_cast_kernel<<<dim3(HD / 32, EE / 32), 256, 0, stream>>>(wk, wkvT, EE, HD);
    transpose_cast_kernel<<<dim3(HD / 32, EE / 32), 256, 0, stream>>>(wv, wkvT + 64 * EE, EE, HD);
    pack_bkv_kernel<<<1, 128, 0, stream>>>(bk, bv, bkv);
    transpose_cast_kernel<<<dim3(EE / 32, EE / 32), 256, 0, stream>>>(wo, woT, EE, EE);

    // 3. qbf = h1 @ wq + bq  [bf16 out]
    gemm_bf16_kernel<<<dim3(EE / GN, MROWS / GM), 256, 0, stream>>>(
        h1b, wqT, bq, nullptr, qbf, MROWS, EE, EE, 0, 1);
    // 4. kv = h1 @ [wk|wv] + [bk|bv]  [fp32 out, N=128]
    gemm_bf16_kernel<<<dim3(1, MROWS / GM), 256, 0, stream>>>(
        h1b, wkvT, bkv, nullptr, kv, MROWS, 128, EE, 0, 0);

    // 5. RoPE on q (in place, bf16, 0.125 folded)
    {
        int total_q = MROWS * HH * 32;
        rope_q_kernel<<<(total_q + 255) / 256, 256, 0, stream>>>(qbf, total_q);
    }
    // 6. kv -> kbf (roped) + vtb (V transposed)
    prep_kv_kernel<<<dim3(SS / 64, BB), 256, 0, stream>>>(kv, kbf, vtb);

    // 7. attention -> ao [bf16]
    attn_mfma_kernel<<<dim3(SS / 64, HH, BB), 256, 0, stream>>>(qbf, kbf, vtb, ao);

    // 8. x2 = ao @ wo + bo + x  [fp32 out]
    gemm_bf16_kernel<<<dim3(EE / GN, MROWS / GM), 256, 0, stream>>>(
        ao, woT, bo, x, x2, MROWS, EE, EE, 1, 0);

    // 9. h2 = rmsnorm(x2, g2)
    rmsnorm_kernel<<<MROWS, 256, 0, stream>>>(x2, g2, h2b, EE);

    // 10. FFN weight transposes (reuse dead qbf slot + wuT region)
    transpose_cast_kernel<<<dim3(FFF / 32, EE / 32), 256, 0, stream>>>(wg, wgT, EE, FFF);
    transpose_cast_kernel<<<dim3(FFF / 32, EE / 32), 256, 0, stream>>>(wu, wuT, EE, FFF);

    // 11. gg = gelu(h2 @ wg + bg)  [bf16]
    gemm_bf16_kernel<<<dim3(FFF / GN, MROWS / GM), 256, 0, stream>>>(
        h2b, wgT, bg, nullptr, gg, MROWS, FFF, EE, 2, 1);

    // 12. gg = (h2 @ wu + bu) * gg  [bf16]
    gemm_bf16_kernel<<<dim3(FFF / GN, MROWS / GM), 256, 0, stream>>>(
        h2b, wuT, bu, gg, gg, MROWS, FFF, EE, 3, 1);

    // 13. wd transpose, then out = gg @ wd + bd + x2  [fp32]
    transpose_cast_kernel<<<dim3(EE / 32, FFF / 32), 256, 0, stream>>>(wd, wdT, FFF, EE);
    gemm_bf16_kernel<<<dim3(EE / GN, MROWS / GM), 256, 0, stream>>>(
        gg, wdT, bd, x2, out, MROWS, EE, FFF, 1, 0);
}